// Round 4
// baseline (378.616 us; speedup 1.0000x reference)
//
#include <hip/hip_runtime.h>
#include <cmath>

#define IN_CH 128
#define NBUCK 128
#define LNMAX 392   // ceil(50048/128); node local id = node>>7
// Cacheable relaxed load/store (compile to plain global ld/st, L1/L2-cacheable).
#define PLW(p)     __hip_atomic_load((p), __ATOMIC_RELAXED, __HIP_MEMORY_SCOPE_WORKGROUP)
#define PSW(p, v)  __hip_atomic_store((p), (v), __ATOMIC_RELAXED, __HIP_MEMORY_SCOPE_WORKGROUP)

typedef unsigned long long ull;
typedef ull  ull2 __attribute__((ext_vector_type(2)));
typedef float f4  __attribute__((ext_vector_type(4)));

// Monotone descending key: smaller key == higher norm; ties -> smaller edge idx
// (matches stable argsort of -norm). All keys distinct. Low 32 bits = edge idx.
__device__ __forceinline__ ull make_key(float norm, int e) {
    unsigned int b = __float_as_uint(norm);
    unsigned int asc = (b & 0x80000000u) ? ~b : (b | 0x80000000u); // monotone-increasing map
    unsigned int desc = ~asc;
    return (((ull)desc) << 32) | (unsigned int)e;
}

// One wave per node: p[n] = dot(x[n], w_src), q[n] = dot(x[n], w_dst), double accum.
// Per-node state init + counter zeroing folded in.
__global__ void proj_kernel(const float* __restrict__ x, const float* __restrict__ w_src,
                            const float* __restrict__ w_dst, float* __restrict__ p,
                            float* __restrict__ q,
                            unsigned int* __restrict__ node_max, double* __restrict__ denom,
                            ull* __restrict__ wsuit, ull* __restrict__ wsh,
                            int* __restrict__ deg,
                            int* __restrict__ cluster, int* __restrict__ partner,
                            float* __restrict__ s_rep, int* __restrict__ bump,
                            int* __restrict__ btail, int N) {
    int gtid = blockIdx.x * blockDim.x + threadIdx.x;
    if (gtid == 0) *bump = 0;
    if (gtid < NBUCK) btail[gtid] = 0;
    if (gtid < N) {
        node_max[gtid] = 0u;       // bits of +0.0f; any positive score has bits > 0
        denom[gtid]    = 0.0;
        wsuit[gtid]    = ~0ULL;
        wsh[gtid]      = ~0ULL;    // probe shadow (plain stores only; wsh >= ws invariant)
        deg[gtid]      = 0;
        cluster[gtid]  = gtid;
        partner[gtid]  = gtid;
        s_rep[gtid]    = 1.0f;
    }
    int wave = gtid >> 6;
    int lane = threadIdx.x & 63;
    if (wave >= N) return;
    float2 xv = ((const float2*)(x + (size_t)wave * IN_CH))[lane];
    float2 ws = ((const float2*)w_src)[lane];
    float2 wd = ((const float2*)w_dst)[lane];
    double ap = (double)xv.x * (double)ws.x + (double)xv.y * (double)ws.y;
    double aq = (double)xv.x * (double)wd.x + (double)xv.y * (double)wd.y;
    #pragma unroll
    for (int off = 32; off > 0; off >>= 1) {
        ap += __shfl_down(ap, off);
        aq += __shfl_down(aq, off);
    }
    if (lane == 0) { p[wave] = (float)ap; q[wave] = (float)aq; }
}

// Fused: edge score + rc pack + 128-bucket build. NO global atomics at all now
// (node_max/denom/deg all move to slot_kernel's LDS passes).
// Entry (pre-slot form): e[0:19] | side[20] | (node>>7)[21:29] | self[30]
// Self-loops (u==v) get one side-0 entry with self=1: they contribute to
// node_max/denom but must NOT enter the adjacency (can't match).
__global__ void score_kernel(const int* __restrict__ row, const int* __restrict__ col,
                             const float* __restrict__ p, const float* __restrict__ q,
                             const float* __restrict__ bptr, float* __restrict__ score,
                             int2* __restrict__ rc, int* __restrict__ btail,
                             unsigned int* __restrict__ bucket, int bcap, int E) {
    __shared__ int cnt[NBUCK];
    __shared__ int gbase[NBUCK];
    int e = blockIdx.x * blockDim.x + threadIdx.x;
    if (threadIdx.x < NBUCK) cnt[threadIdx.x] = 0;
    __syncthreads();
    bool inb = e < E;
    int u = 0, v = 0, l1 = -1, l2 = -1, h1 = 0, h2 = 0;
    unsigned int selfbit = 0;
    if (inb) {
        u = row[e]; v = col[e];
        rc[e] = make_int2(u, v);
        float s = p[u] + q[v] + bptr[0];
        score[e] = s;
        selfbit = (u == v) ? (1u << 30) : 0u;
        h1 = u & (NBUCK - 1); l1 = atomicAdd(&cnt[h1], 1);   // side-0 entry (always)
        if (u != v) {
            h2 = v & (NBUCK - 1); l2 = atomicAdd(&cnt[h2], 1);
        }
    }
    __syncthreads();
    if (threadIdx.x < NBUCK) gbase[threadIdx.x] = atomicAdd(&btail[threadIdx.x], cnt[threadIdx.x]);
    __syncthreads();
    if (l1 >= 0) bucket[(size_t)h1 * bcap + gbase[h1] + l1] =
        (unsigned int)e | ((unsigned int)(u >> 7) << 21) | selfbit;
    if (l2 >= 0) bucket[(size_t)h2 * bcap + gbase[h2] + l2] =
        (unsigned int)e | (1u << 20) | ((unsigned int)(v >> 7) << 21);
}

// One WG per bucket; bucket b owns nodes n with (n & 127) == b (<=392 of them).
// Pass 1: node_max via LDS atomicMax over side-0 entries (incl. self).
// Pass 2: denom via LDS f64 atomicAdd (identical per-edge value as before:
// (double)(float)exp((double)(s-m))); slot assignment via LDS hist; entries
// rewritten to slot form e[0:19]|side[20]|slot[21:31]; self entries ->
// 0xFFFFFFFF sentinel (e<2^20 makes this unambiguous). Then write node_max/
// denom/deg once per owned node. Replaces ALL per-edge global atomics.
__global__ void slot_kernel(unsigned int* __restrict__ bucket, const int* __restrict__ btail,
                            int bcap, const float* __restrict__ score,
                            unsigned int* __restrict__ node_max, double* __restrict__ denom,
                            int* __restrict__ deg, int N) {
    __shared__ int hist[LNMAX];
    __shared__ unsigned int maxv[LNMAX];
    __shared__ double dden[LNMAX];
    int b = blockIdx.x;
    for (int i = threadIdx.x; i < LNMAX; i += blockDim.x) {
        hist[i] = 0; maxv[i] = 0u; dden[i] = 0.0;
    }
    __syncthreads();
    int n = btail[b];
    unsigned int* bk = bucket + (size_t)b * bcap;
    // pass 1: per-node max of positive source-side scores
    for (int i = threadIdx.x; i < n; i += blockDim.x) {
        unsigned int ent = bk[i];
        if (!(ent & (1u << 20))) {                 // side 0 (incl. self)
            int e = (int)(ent & 0xfffffu);
            float s = score[e];
            if (s > 0.0f) {
                int ln = (int)((ent >> 21) & 0x1ffu);
                atomicMax(&maxv[ln], __float_as_uint(s));
            }
        }
    }
    __syncthreads();
    // pass 2: denom accumulate + slot assign + rewrite
    for (int i = threadIdx.x; i < n; i += blockDim.x) {
        unsigned int ent = bk[i];
        int ln = (int)((ent >> 21) & 0x1ffu);
        if (!(ent & (1u << 20))) {                 // side 0: denom contribution
            unsigned int mb = maxv[ln];
            int e = (int)(ent & 0xfffffu);
            float s = score[e];
            if (mb != 0u && s > 0.0f) {
                float m = __uint_as_float(mb);
                float ev = (float)exp((double)(s - m));   // same value as old exp_alloc
                atomicAdd(&dden[ln], (double)ev);
            }
        }
        if (ent & (1u << 30)) {
            bk[i] = 0xFFFFFFFFu;                   // self: no adjacency slot
        } else {
            int slot = atomicAdd(&hist[ln], 1);
            bk[i] = (ent & 0x1fffffu) | ((unsigned int)slot << 21);
        }
    }
    __syncthreads();
    for (int ln = threadIdx.x; ln < LNMAX; ln += blockDim.x) {
        int node = (ln << 7) | b;
        if (node < N) {
            node_max[node] = maxv[ln];
            denom[node]    = dden[ln];
            deg[node]      = hist[ln];
        }
    }
}

// Phase A: finalize norm (identical arithmetic to the old exp_alloc+norm_key
// pair: ev=(float)exp((double)(s-m)); nv=ev/d+0.5f) + coalesced key write.
// Per-node CSR seg allocation folded in (64B-padded segments, order-free bump).
__global__ void norm_key_kernel(const int* __restrict__ row, const float* __restrict__ score,
                                const unsigned int* __restrict__ node_max,
                                const double* __restrict__ denom, float* __restrict__ norm,
                                ull* __restrict__ keyn, const int* __restrict__ deg,
                                int* __restrict__ bump, int2* __restrict__ seg,
                                int E, int N) {
    int e = blockIdx.x * blockDim.x + threadIdx.x;
    if (e < N) {
        int d = deg[e];
        int lo = atomicAdd(bump, (d + 3) & ~3);   // 64B-aligned segments
        seg[e] = make_int2(lo, lo + d);
    }
    if (e >= E) return;
    int u = row[e];
    unsigned int mb = node_max[u];
    float nv;
    if (mb != 0u) {
        float s = score[e];
        if (s > 0.0f) {
            float m = __uint_as_float(mb);
            float ev = (float)exp((double)(s - m));
            float d = (float)denom[u];
            nv = ev / d + 0.5f;                   // exact f32 div + add, same as ref
        } else {
            nv = 0.0f;
        }
    } else {
        nv = score[e];                            // raw score for rows with no positive edge
    }
    norm[e] = nv;
    keyn[e] = make_key(nv, e);
}

// Phase B: XCD-pinned CSR scatter, atomic-free (pos = seg.lo + slot).
// bucket b -> XCD b&7 (node&7 preserved) so all writers of a node's
// line-aligned segment share one XCD.
__global__ void csr_scatter_kernel(const unsigned int* __restrict__ bucket,
                                   const int* __restrict__ btail, int bcap,
                                   const ull* __restrict__ keyn, const int2* __restrict__ rc,
                                   const int2* __restrict__ seg,
                                   ull2* __restrict__ adj, int bpx) {
    int xcd = blockIdx.x & 7;
    int sub = blockIdx.x >> 3;
    for (int bb = 0; bb < NBUCK / 8; ++bb) {
        int b = xcd + (bb << 3);
        int n = btail[b];
        const unsigned int* bk = bucket + (size_t)b * bcap;
        for (int i = sub * blockDim.x + threadIdx.x; i < n; i += bpx * blockDim.x) {
            unsigned int ent = bk[i];
            if (ent == 0xFFFFFFFFu) continue;      // self-loop sentinel
            int e    = (int)(ent & 0xfffffu);
            int side = (int)((ent >> 20) & 1u);
            int slot = (int)(ent >> 21);
            int2 pr = rc[e];
            int dst = side ? pr.y : pr.x;
            int nb  = side ? pr.x : pr.y;
            ull2 w; w.x = keyn[e]; w.y = (ull)nb;
            adj[seg[dst].x + slot] = w;
        }
    }
}

// ---- Suitor matching (Manne-Bisseling), 32-lane-group-per-node.
// R4: probes read wsh[] (a plain-store mirror of ws) instead of ws itself.
// ws lines are perpetually invalidated by device-scope atomicMins (R3 lesson:
// scope demotion didn't help because the ATOMICS kill the lines), so probing
// ws costs a past-L2 fetch ~40% of the time. wsh is written only by plain
// stores -> caches normally. Invariant wsh[v] >= ws[v] (every stored value is
// min(old,bk) = a true ws value at store time; ws monotone-decreasing), so
// filtering by wsh only discards provably-infeasible candidates. Progress is
// staleness-independent via excl (a rejection proves ws[bv] <= bk; proposal
// keys strictly increase between takeovers). Fixed point of ws unchanged.
__global__ void suitor_kernel(const int2* __restrict__ seg,
                              const ull2* __restrict__ adj,
                              const int2* __restrict__ rc,
                              ull* __restrict__ ws, ull* __restrict__ wsh, int N) {
    int grp  = (blockIdx.x * blockDim.x + threadIdx.x) >> 5;
    int lane = threadIdx.x & 31;
    if (grp >= N) return;
    int cur = grp;
    int2 lohi;
    ull excl = 0ULL;          // keys <= excl proven infeasible for cur (monotone)
    ull lk = ~0ULL;           // lane-local best candidate key
    int lv = -1;              // its neighbor
    bool reload = true;
    for (int guard = 0; guard < 1000000; ++guard) {
        if (reload) {
            lohi = seg[cur];
            excl = 0ULL;
            lk = ~0ULL; lv = -1;
            for (int i = lohi.x + lane; i < lohi.y; i += 32) {
                ull2 ent = adj[i];              // coalesced 16B
                ull k = ent.x;
                if (k < lk) {
                    int v = (int)ent.y;
                    if (k < PLW(&wsh[v])) { lk = k; lv = v; }  // cached shadow probe
                }
            }
            reload = false;
        } else if (lk != ~0ULL && lk <= excl) {
            // this lane owned the rejected key: recompute from its entries
            lk = ~0ULL; lv = -1;
            for (int i = lohi.x + lane; i < lohi.y; i += 32) {
                ull2 ent = adj[i];              // L1/L2-hot re-read, 1-2 entries
                ull k = ent.x;
                if (k > excl && k < lk) {
                    int v = (int)ent.y;
                    if (k < PLW(&wsh[v])) { lk = k; lv = v; }
                }
            }
        }
        // group-wide butterfly min-reduce with payload (width 32)
        ull bk = lk; int bv = lv;
        #pragma unroll
        for (int off = 16; off > 0; off >>= 1) {
            ull ok = __shfl_xor(bk, off, 32);
            int ov = __shfl_xor(bv, off, 32);
            if (ok < bk) { bk = ok; bv = ov; }
        }
        if (bk == ~0ULL) break;             // no feasible proposal: cur stays unmatched
        ull old;
        if (lane == 0) {
            old = atomicMin(&ws[bv], bk);
            PSW(&wsh[bv], old < bk ? old : bk);   // refresh shadow (plain store)
        }
        old = __shfl(old, 0, 32);
        if (old <= bk) {
            excl = bk;                      // proven infeasible; next proposal key > bk
            continue;
        }
        // accepted; take over the displaced proposer (atomicMin hands each
        // displaced value to exactly one group)
        if (old == ~0ULL) break;
        int e = (int)(old & 0xffffffffu);
        int2 pr = rc[e];                    // same address across group -> broadcast
        cur = pr.x ^ pr.y ^ bv;             // displaced proposer = other endpoint of e
        reload = true;
    }
}

// Node-centric extract: each node's standing proposal names its edge; matched
// iff mutual (ws[a]==ws[b]==k). The a-side thread writes (once per pair).
__global__ void extract_kernel(const int2* __restrict__ rc, const float* __restrict__ norm,
                               const ull* __restrict__ ws,
                               int* __restrict__ cluster, int* __restrict__ partner,
                               float* __restrict__ s_rep, int N) {
    int w = blockIdx.x * blockDim.x + threadIdx.x;
    if (w >= N) return;
    ull k = ws[w];
    if (k == ~0ULL) return;
    int e = (int)(k & 0xffffffffu);
    int2 pr = rc[e];                        // w is an endpoint of e
    int a = pr.x, b = pr.y;
    if (w != a) return;                     // b-side duplicate: skip
    if (ws[b] == k) {                       // mutual => matched (ws[a]==k by construction)
        cluster[b] = a;                     // b merged into rep a (ref: cluster[c_s]=r_s)
        partner[a] = b;
        s_rep[a]   = norm[e];
    }
}

// Fused epilogue: blocks [0, NB1) do new_x/cluster/is_rep; blocks [NB1, ..) do
// edges. nt ONLY on the fully-coalesced f4 newx stream.
__global__ void out_kernel(const float* __restrict__ x, const int* __restrict__ cluster,
                           const int* __restrict__ partner, const float* __restrict__ s_rep,
                           const int* __restrict__ row, const int* __restrict__ col,
                           const float* __restrict__ w,
                           float* __restrict__ out_newx, float* __restrict__ out_cluster,
                           float* __restrict__ out_isrep, float* __restrict__ out_nrow,
                           float* __restrict__ out_ncol, float* __restrict__ out_valid,
                           float* __restrict__ out_w, int N, int E, int NB1) {
    if ((int)blockIdx.x < NB1) {
        int t = blockIdx.x * blockDim.x + threadIdx.x;
        if (t >= N * (IN_CH / 4)) return;
        int n = t >> 5;            // IN_CH/4 == 32 float4 per node
        int c = (t & 31) * 4;
        int cl = cluster[n];
        if ((t & 31) == 0) {
            out_cluster[n] = (float)cl;
            out_isrep[n]   = (cl == n) ? 1.0f : 0.0f;
        }
        f4 o;
        int v = partner[n];
        if (cl != n) {
            o = (f4)0.0f;                                     // merged-away node row
        } else if (v != n) {
            float s = s_rep[n];
            f4 xu = *(const f4*)(x + (size_t)n * IN_CH + c);
            f4 xv = *(const f4*)(x + (size_t)v * IN_CH + c);
            o = (xu + xv) * s + xv;
        } else {
            o = *(const f4*)(x + (size_t)n * IN_CH + c);      // untouched node
        }
        __builtin_nontemporal_store(o, (f4*)out_newx + t);
    } else {
        int e = (blockIdx.x - NB1) * blockDim.x + threadIdx.x;
        if (e >= E) return;
        int nr = cluster[row[e]];
        int nc = cluster[col[e]];
        out_nrow[e]  = (float)nr;
        out_ncol[e]  = (float)nc;
        out_valid[e] = (nr != nc) ? 1.0f : 0.0f;
        out_w[e]     = w[e];
    }
}

extern "C" void kernel_launch(void* const* d_in, const int* in_sizes, int n_in_args,
                              void* d_out, int out_size, void* d_ws, size_t ws_size,
                              hipStream_t stream) {
    const float* x     = (const float*)d_in[0];
    const float* w_src = (const float*)d_in[1];
    const float* w_dst = (const float*)d_in[2];
    const float* bptr  = (const float*)d_in[3];
    const int*   ei    = (const int*)d_in[4];
    const float* ew    = (const float*)d_in[5];
    const int N = in_sizes[0] / IN_CH;
    const int E = in_sizes[5];
    const int* row = ei;
    const int* col = ei + E;

    char* wsb = (char*)d_ws;
    size_t off = 0;
    auto alloc = [&](size_t bytes) -> void* {
        off = (off + 255) & ~(size_t)255;
        void* ptr = wsb + off;
        off += bytes;
        return ptr;
    };
    // 128 buckets: expected (2E)/128 = 12500 entries each, sigma ~110; big slack.
    const int bcap = E / 64 + E / 512 + 1024;
    float*        score    = (float*)alloc((size_t)E * 4);
    float*        norm     = (float*)alloc((size_t)E * 4);
    int2*         rc       = (int2*)alloc((size_t)E * 8);
    ull*          keyn     = (ull*)alloc((size_t)E * 8);
    ull2*         adj      = (ull2*)alloc(((size_t)2 * E + 4 * N) * 16);
    unsigned int* bucket   = (unsigned int*)alloc((size_t)NBUCK * bcap * 4);
    unsigned int* node_max = (unsigned int*)alloc((size_t)N * 4);
    double*       denom    = (double*)alloc((size_t)N * 8);
    ull*          wsuit    = (ull*)alloc((size_t)N * 8);
    ull*          wsh      = (ull*)alloc((size_t)N * 8);
    int*          deg      = (int*)alloc((size_t)N * 4);
    int2*         seg      = (int2*)alloc((size_t)N * 8);
    int*          cluster  = (int*)alloc((size_t)N * 4);
    int*          partner  = (int*)alloc((size_t)N * 4);
    float*        s_rep    = (float*)alloc((size_t)N * 4);
    float*        pbuf     = (float*)alloc((size_t)N * 4);
    float*        qbuf     = (float*)alloc((size_t)N * 4);
    int*          bump     = (int*)alloc(64);
    int*          btail    = (int*)alloc((size_t)NBUCK * 4);

    // Output layout: new_x[N*128] | cluster[N] | is_rep[N] | new_row[E] | new_col[E] | edge_valid[E] | edge_weight[E]
    float* out       = (float*)d_out;
    float* o_newx    = out;
    float* o_cluster = out + (size_t)N * IN_CH;
    float* o_isrep   = o_cluster + N;
    float* o_nrow    = o_isrep + N;
    float* o_ncol    = o_nrow + E;
    float* o_valid   = o_ncol + E;
    float* o_w       = o_valid + E;

    const int T = 256;
    const int TS = 512;
    hipLaunchKernelGGL(proj_kernel, dim3((N * 64 + T - 1) / T), dim3(T), 0, stream,
                       x, w_src, w_dst, pbuf, qbuf,
                       node_max, denom, wsuit, wsh, deg, cluster, partner, s_rep, bump, btail, N);
    hipLaunchKernelGGL(score_kernel, dim3((E + TS - 1) / TS), dim3(TS), 0, stream,
                       row, col, pbuf, qbuf, bptr, score, rc,
                       btail, bucket, bcap, E);
    hipLaunchKernelGGL(slot_kernel, dim3(NBUCK), dim3(512), 0, stream,
                       bucket, btail, bcap, score, node_max, denom, deg, N);
    hipLaunchKernelGGL(norm_key_kernel, dim3((E + T - 1) / T), dim3(T), 0, stream,
                       row, score, node_max, denom, norm, keyn, deg, bump, seg, E, N);
    const int bpx = 40;                     // blocks per XCD slot
    hipLaunchKernelGGL(csr_scatter_kernel, dim3(8 * bpx), dim3(T), 0, stream,
                       bucket, btail, bcap, keyn, rc, seg, adj, bpx);
    hipLaunchKernelGGL(suitor_kernel, dim3((N * 32 + T - 1) / T), dim3(T), 0, stream,
                       seg, adj, rc, wsuit, wsh, N);
    hipLaunchKernelGGL(extract_kernel, dim3((N + T - 1) / T), dim3(T), 0, stream,
                       rc, norm, wsuit, cluster, partner, s_rep, N);
    const int NB1 = (N * 32 + T - 1) / T;
    const int NB2 = (E + T - 1) / T;
    hipLaunchKernelGGL(out_kernel, dim3(NB1 + NB2), dim3(T), 0, stream,
                       x, cluster, partner, s_rep, row, col, ew,
                       o_newx, o_cluster, o_isrep, o_nrow, o_ncol, o_valid, o_w, N, E, NB1);
    (void)ws_size; (void)out_size; (void)n_in_args;
}

// Round 5
// 355.996 us; speedup vs baseline: 1.0635x; 1.0635x over previous
//
#include <hip/hip_runtime.h>
#include <cmath>

#define IN_CH 128
#define NBUCK 128
#define LNMAX 392   // ceil(50048/128); node local id = node>>7
// Cacheable (L1/L2) relaxed probe: ws is monotone-decreasing so stale reads are
// stale-HIGH => safe (can only cause a rejected proposal, never a wrong skip).
#define PLW(p) __hip_atomic_load((p), __ATOMIC_RELAXED, __HIP_MEMORY_SCOPE_WORKGROUP)

typedef unsigned long long ull;
typedef ull  ull2 __attribute__((ext_vector_type(2)));
typedef float f4  __attribute__((ext_vector_type(4)));

// Monotone descending key: smaller key == higher norm; ties -> smaller edge idx
// (matches stable argsort of -norm). All keys distinct. Low 32 bits = edge idx.
__device__ __forceinline__ ull make_key(float norm, int e) {
    unsigned int b = __float_as_uint(norm);
    unsigned int asc = (b & 0x80000000u) ? ~b : (b | 0x80000000u); // monotone-increasing map
    unsigned int desc = ~asc;
    return (((ull)desc) << 32) | (unsigned int)e;
}

// One wave per node: p[n] = dot(x[n], w_src), q[n] = dot(x[n], w_dst), double accum.
// Per-node state init + counter zeroing folded in.
__global__ void proj_kernel(const float* __restrict__ x, const float* __restrict__ w_src,
                            const float* __restrict__ w_dst, float* __restrict__ p,
                            float* __restrict__ q,
                            ull* __restrict__ wsuit,
                            int* __restrict__ cluster, int* __restrict__ partner,
                            float* __restrict__ s_rep, int* __restrict__ bump,
                            int* __restrict__ btail, int N) {
    int gtid = blockIdx.x * blockDim.x + threadIdx.x;
    if (gtid == 0) *bump = 0;
    if (gtid < NBUCK) btail[gtid] = 0;
    if (gtid < N) {
        wsuit[gtid]    = ~0ULL;
        cluster[gtid]  = gtid;
        partner[gtid]  = gtid;
        s_rep[gtid]    = 1.0f;
    }
    int wave = gtid >> 6;
    int lane = threadIdx.x & 63;
    if (wave >= N) return;
    float2 xv = ((const float2*)(x + (size_t)wave * IN_CH))[lane];
    float2 ws = ((const float2*)w_src)[lane];
    float2 wd = ((const float2*)w_dst)[lane];
    double ap = (double)xv.x * (double)ws.x + (double)xv.y * (double)ws.y;
    double aq = (double)xv.x * (double)wd.x + (double)xv.y * (double)wd.y;
    #pragma unroll
    for (int off = 32; off > 0; off >>= 1) {
        ap += __shfl_down(ap, off);
        aq += __shfl_down(aq, off);
    }
    if (lane == 0) { p[wave] = (float)ap; q[wave] = (float)aq; }
}

// Fused: edge score + rc pack + 128-bucket build. No global atomics
// (node_max/denom/deg/seg all live in slot_kernel's LDS passes).
// Entry (pre-slot form): e[0:19] | side[20] | (node>>7)[21:29] | self[30]
// Self-loops (u==v) get one side-0 entry with self=1: they contribute to
// node_max/denom but must NOT enter the adjacency (can't match).
__global__ void score_kernel(const int* __restrict__ row, const int* __restrict__ col,
                             const float* __restrict__ p, const float* __restrict__ q,
                             const float* __restrict__ bptr, float* __restrict__ score,
                             int2* __restrict__ rc, int* __restrict__ btail,
                             unsigned int* __restrict__ bucket, int bcap, int E) {
    __shared__ int cnt[NBUCK];
    __shared__ int gbase[NBUCK];
    int e = blockIdx.x * blockDim.x + threadIdx.x;
    if (threadIdx.x < NBUCK) cnt[threadIdx.x] = 0;
    __syncthreads();
    bool inb = e < E;
    int u = 0, v = 0, l1 = -1, l2 = -1, h1 = 0, h2 = 0;
    unsigned int selfbit = 0;
    if (inb) {
        u = row[e]; v = col[e];
        rc[e] = make_int2(u, v);
        float s = p[u] + q[v] + bptr[0];
        score[e] = s;
        selfbit = (u == v) ? (1u << 30) : 0u;
        h1 = u & (NBUCK - 1); l1 = atomicAdd(&cnt[h1], 1);   // side-0 entry (always)
        if (u != v) {
            h2 = v & (NBUCK - 1); l2 = atomicAdd(&cnt[h2], 1);
        }
    }
    __syncthreads();
    if (threadIdx.x < NBUCK) gbase[threadIdx.x] = atomicAdd(&btail[threadIdx.x], cnt[threadIdx.x]);
    __syncthreads();
    if (l1 >= 0) bucket[(size_t)h1 * bcap + gbase[h1] + l1] =
        (unsigned int)e | ((unsigned int)(u >> 7) << 21) | selfbit;
    if (l2 >= 0) bucket[(size_t)h2 * bcap + gbase[h2] + l2] =
        (unsigned int)e | (1u << 20) | ((unsigned int)(v >> 7) << 21);
}

// One WG (512 thr) per bucket; bucket b owns nodes n with (n&127)==b (<=391).
// Pass 1: node_max via LDS atomicMax over side-0 entries (incl. self).
// Pass 2: denom via LDS f64 atomicAdd (identical per-edge value:
// (double)(float)exp((double)(s-m))); slot assignment via LDS hist; entries
// rewritten to slot form e[0:19]|side[20]|slot[21:31]; self -> 0xFFFFFFFF.
// Pass 3 (R5): per-bucket LDS prefix-scan of 64B-padded degrees -> ONE global
// atomicAdd(bump, total) per bucket (128 total, replaces 50K same-address
// RMWs), seg[node] = base + exclusive prefix. Segments stay disjoint,
// 4-entry-aligned; adjacency content (and thus output) unchanged.
__global__ void slot_kernel(unsigned int* __restrict__ bucket, const int* __restrict__ btail,
                            int bcap, const float* __restrict__ score,
                            unsigned int* __restrict__ node_max, double* __restrict__ denom,
                            int* __restrict__ bump, int2* __restrict__ seg, int N) {
    __shared__ int hist[LNMAX];
    __shared__ unsigned int maxv[LNMAX];
    __shared__ double dden[LNMAX];
    __shared__ int scan[512];
    __shared__ int basesh;
    int b = blockIdx.x;
    int t = threadIdx.x;
    for (int i = t; i < LNMAX; i += blockDim.x) {
        hist[i] = 0; maxv[i] = 0u; dden[i] = 0.0;
    }
    __syncthreads();
    int n = btail[b];
    unsigned int* bk = bucket + (size_t)b * bcap;
    // pass 1: per-node max of positive source-side scores
    for (int i = t; i < n; i += blockDim.x) {
        unsigned int ent = bk[i];
        if (!(ent & (1u << 20))) {                 // side 0 (incl. self)
            int e = (int)(ent & 0xfffffu);
            float s = score[e];
            if (s > 0.0f) {
                int ln = (int)((ent >> 21) & 0x1ffu);
                atomicMax(&maxv[ln], __float_as_uint(s));
            }
        }
    }
    __syncthreads();
    // pass 2: denom accumulate + slot assign + rewrite
    for (int i = t; i < n; i += blockDim.x) {
        unsigned int ent = bk[i];
        int ln = (int)((ent >> 21) & 0x1ffu);
        if (!(ent & (1u << 20))) {                 // side 0: denom contribution
            unsigned int mb = maxv[ln];
            int e = (int)(ent & 0xfffffu);
            float s = score[e];
            if (mb != 0u && s > 0.0f) {
                float m = __uint_as_float(mb);
                float ev = (float)exp((double)(s - m));
                atomicAdd(&dden[ln], (double)ev);
            }
        }
        if (ent & (1u << 30)) {
            bk[i] = 0xFFFFFFFFu;                   // self: no adjacency slot
        } else {
            int slot = atomicAdd(&hist[ln], 1);
            bk[i] = (ent & 0x1fffffu) | ((unsigned int)slot << 21);
        }
    }
    __syncthreads();
    // pass 3: seg allocation via LDS inclusive scan (blockDim == 512 >= LNMAX)
    int node = (t << 7) | b;
    int d  = (t < LNMAX && node < N) ? hist[t] : 0;
    int pd = (d + 3) & ~3;                         // 64B-padded segment size
    scan[t] = pd;
    __syncthreads();
    #pragma unroll
    for (int off = 1; off < 512; off <<= 1) {
        int add = (t >= off) ? scan[t - off] : 0;
        __syncthreads();
        scan[t] += add;
        __syncthreads();
    }
    if (t == 511) basesh = atomicAdd(bump, scan[511]);   // ONE global RMW/bucket
    __syncthreads();
    if (t < LNMAX && node < N) {
        int lo = basesh + scan[t] - pd;
        seg[node]      = make_int2(lo, lo + d);
        node_max[node] = maxv[t];
        denom[node]    = dden[t];
    }
}

// Phase A: finalize norm (identical arithmetic to ref: ev=(float)exp((double)
// (s-m)); nv=ev/d+0.5f) + coalesced key write. Pure streaming edge kernel now.
__global__ void norm_key_kernel(const int* __restrict__ row, const float* __restrict__ score,
                                const unsigned int* __restrict__ node_max,
                                const double* __restrict__ denom, float* __restrict__ norm,
                                ull* __restrict__ keyn, int E) {
    int e = blockIdx.x * blockDim.x + threadIdx.x;
    if (e >= E) return;
    int u = row[e];
    unsigned int mb = node_max[u];
    float nv;
    if (mb != 0u) {
        float s = score[e];
        if (s > 0.0f) {
            float m = __uint_as_float(mb);
            float ev = (float)exp((double)(s - m));
            float d = (float)denom[u];
            nv = ev / d + 0.5f;                   // exact f32 div + add, same as ref
        } else {
            nv = 0.0f;
        }
    } else {
        nv = score[e];                            // raw score for rows with no positive edge
    }
    norm[e] = nv;
    keyn[e] = make_key(nv, e);
}

// Phase B: XCD-pinned CSR scatter, atomic-free (pos = seg.lo + slot).
// bucket b -> XCD b&7 (node&7 preserved) so all writers of a node's
// line-aligned segment share one XCD.
__global__ void csr_scatter_kernel(const unsigned int* __restrict__ bucket,
                                   const int* __restrict__ btail, int bcap,
                                   const ull* __restrict__ keyn, const int2* __restrict__ rc,
                                   const int2* __restrict__ seg,
                                   ull2* __restrict__ adj, int bpx) {
    int xcd = blockIdx.x & 7;
    int sub = blockIdx.x >> 3;
    for (int bb = 0; bb < NBUCK / 8; ++bb) {
        int b = xcd + (bb << 3);
        int n = btail[b];
        const unsigned int* bk = bucket + (size_t)b * bcap;
        for (int i = sub * blockDim.x + threadIdx.x; i < n; i += bpx * blockDim.x) {
            unsigned int ent = bk[i];
            if (ent == 0xFFFFFFFFu) continue;      // self-loop sentinel
            int e    = (int)(ent & 0xfffffu);
            int side = (int)((ent >> 20) & 1u);
            int slot = (int)(ent >> 21);
            int2 pr = rc[e];
            int dst = side ? pr.y : pr.x;
            int nb  = side ? pr.x : pr.y;
            ull2 w; w.x = keyn[e]; w.y = (ull)nb;
            adj[seg[dst].x + slot] = w;
        }
    }
}

// ---- Suitor matching (Manne-Bisseling), 32-lane-group-per-node. R3 version
// (best measured): cacheable probes of ws directly (stale-high => safe filter),
// progress guaranteed by excl (a rejection proves ws[bv] <= bk; proposal keys
// strictly increase between takeovers). R4's wsh shadow REVERTED: remote-L1
// staleness caused extra serialized rounds that cost more than the probe
// fetches it saved. Fixed point of ws (and output) unchanged.
__global__ void suitor_kernel(const int2* __restrict__ seg,
                              const ull2* __restrict__ adj,
                              const int2* __restrict__ rc,
                              ull* __restrict__ ws, int N) {
    int grp  = (blockIdx.x * blockDim.x + threadIdx.x) >> 5;
    int lane = threadIdx.x & 31;
    if (grp >= N) return;
    int cur = grp;
    int2 lohi;
    ull excl = 0ULL;          // keys <= excl proven infeasible for cur (monotone)
    ull lk = ~0ULL;           // lane-local best candidate key
    int lv = -1;              // its neighbor
    bool reload = true;
    for (int guard = 0; guard < 1000000; ++guard) {
        if (reload) {
            lohi = seg[cur];
            excl = 0ULL;
            lk = ~0ULL; lv = -1;
            for (int i = lohi.x + lane; i < lohi.y; i += 32) {
                ull2 ent = adj[i];              // coalesced 16B
                ull k = ent.x;
                if (k < lk) {
                    int v = (int)ent.y;
                    if (k < PLW(&ws[v])) { lk = k; lv = v; }  // cached probe
                }
            }
            reload = false;
        } else if (lk != ~0ULL && lk <= excl) {
            // this lane owned the rejected key: recompute from its entries
            lk = ~0ULL; lv = -1;
            for (int i = lohi.x + lane; i < lohi.y; i += 32) {
                ull2 ent = adj[i];              // L1/L2-hot re-read, 1-2 entries
                ull k = ent.x;
                if (k > excl && k < lk) {
                    int v = (int)ent.y;
                    if (k < PLW(&ws[v])) { lk = k; lv = v; }
                }
            }
        }
        // group-wide butterfly min-reduce with payload (width 32)
        ull bk = lk; int bv = lv;
        #pragma unroll
        for (int off = 16; off > 0; off >>= 1) {
            ull ok = __shfl_xor(bk, off, 32);
            int ov = __shfl_xor(bv, off, 32);
            if (ok < bk) { bk = ok; bv = ov; }
        }
        if (bk == ~0ULL) break;             // no feasible proposal: cur stays unmatched
        ull old;
        if (lane == 0) old = atomicMin(&ws[bv], bk);
        old = __shfl(old, 0, 32);
        if (old <= bk) {
            excl = bk;                      // proven infeasible; next proposal key > bk
            continue;
        }
        // accepted; take over the displaced proposer (atomicMin hands each
        // displaced value to exactly one group)
        if (old == ~0ULL) break;
        int e = (int)(old & 0xffffffffu);
        int2 pr = rc[e];                    // same address across group -> broadcast
        cur = pr.x ^ pr.y ^ bv;             // displaced proposer = other endpoint of e
        reload = true;
    }
}

// Node-centric extract: each node's standing proposal names its edge; matched
// iff mutual (ws[a]==ws[b]==k). The a-side thread writes (once per pair).
__global__ void extract_kernel(const int2* __restrict__ rc, const float* __restrict__ norm,
                               const ull* __restrict__ ws,
                               int* __restrict__ cluster, int* __restrict__ partner,
                               float* __restrict__ s_rep, int N) {
    int w = blockIdx.x * blockDim.x + threadIdx.x;
    if (w >= N) return;
    ull k = ws[w];
    if (k == ~0ULL) return;
    int e = (int)(k & 0xffffffffu);
    int2 pr = rc[e];                        // w is an endpoint of e
    int a = pr.x, b = pr.y;
    if (w != a) return;                     // b-side duplicate: skip
    if (ws[b] == k) {                       // mutual => matched (ws[a]==k by construction)
        cluster[b] = a;                     // b merged into rep a (ref: cluster[c_s]=r_s)
        partner[a] = b;
        s_rep[a]   = norm[e];
    }
}

// Fused epilogue: blocks [0, NB1) do new_x/cluster/is_rep; blocks [NB1, ..) do
// edges. nt ONLY on the fully-coalesced f4 newx stream.
__global__ void out_kernel(const float* __restrict__ x, const int* __restrict__ cluster,
                           const int* __restrict__ partner, const float* __restrict__ s_rep,
                           const int* __restrict__ row, const int* __restrict__ col,
                           const float* __restrict__ w,
                           float* __restrict__ out_newx, float* __restrict__ out_cluster,
                           float* __restrict__ out_isrep, float* __restrict__ out_nrow,
                           float* __restrict__ out_ncol, float* __restrict__ out_valid,
                           float* __restrict__ out_w, int N, int E, int NB1) {
    if ((int)blockIdx.x < NB1) {
        int t = blockIdx.x * blockDim.x + threadIdx.x;
        if (t >= N * (IN_CH / 4)) return;
        int n = t >> 5;            // IN_CH/4 == 32 float4 per node
        int c = (t & 31) * 4;
        int cl = cluster[n];
        if ((t & 31) == 0) {
            out_cluster[n] = (float)cl;
            out_isrep[n]   = (cl == n) ? 1.0f : 0.0f;
        }
        f4 o;
        int v = partner[n];
        if (cl != n) {
            o = (f4)0.0f;                                     // merged-away node row
        } else if (v != n) {
            float s = s_rep[n];
            f4 xu = *(const f4*)(x + (size_t)n * IN_CH + c);
            f4 xv = *(const f4*)(x + (size_t)v * IN_CH + c);
            o = (xu + xv) * s + xv;
        } else {
            o = *(const f4*)(x + (size_t)n * IN_CH + c);      // untouched node
        }
        __builtin_nontemporal_store(o, (f4*)out_newx + t);
    } else {
        int e = (blockIdx.x - NB1) * blockDim.x + threadIdx.x;
        if (e >= E) return;
        int nr = cluster[row[e]];
        int nc = cluster[col[e]];
        out_nrow[e]  = (float)nr;
        out_ncol[e]  = (float)nc;
        out_valid[e] = (nr != nc) ? 1.0f : 0.0f;
        out_w[e]     = w[e];
    }
}

extern "C" void kernel_launch(void* const* d_in, const int* in_sizes, int n_in_args,
                              void* d_out, int out_size, void* d_ws, size_t ws_size,
                              hipStream_t stream) {
    const float* x     = (const float*)d_in[0];
    const float* w_src = (const float*)d_in[1];
    const float* w_dst = (const float*)d_in[2];
    const float* bptr  = (const float*)d_in[3];
    const int*   ei    = (const int*)d_in[4];
    const float* ew    = (const float*)d_in[5];
    const int N = in_sizes[0] / IN_CH;
    const int E = in_sizes[5];
    const int* row = ei;
    const int* col = ei + E;

    char* wsb = (char*)d_ws;
    size_t off = 0;
    auto alloc = [&](size_t bytes) -> void* {
        off = (off + 255) & ~(size_t)255;
        void* ptr = wsb + off;
        off += bytes;
        return ptr;
    };
    // 128 buckets: expected (2E)/128 = 12500 entries each, sigma ~110; big slack.
    const int bcap = E / 64 + E / 512 + 1024;
    float*        score    = (float*)alloc((size_t)E * 4);
    float*        norm     = (float*)alloc((size_t)E * 4);
    int2*         rc       = (int2*)alloc((size_t)E * 8);
    ull*          keyn     = (ull*)alloc((size_t)E * 8);
    ull2*         adj      = (ull2*)alloc(((size_t)2 * E + 4 * N) * 16);
    unsigned int* bucket   = (unsigned int*)alloc((size_t)NBUCK * bcap * 4);
    unsigned int* node_max = (unsigned int*)alloc((size_t)N * 4);
    double*       denom    = (double*)alloc((size_t)N * 8);
    ull*          wsuit    = (ull*)alloc((size_t)N * 8);
    int2*         seg      = (int2*)alloc((size_t)N * 8);
    int*          cluster  = (int*)alloc((size_t)N * 4);
    int*          partner  = (int*)alloc((size_t)N * 4);
    float*        s_rep    = (float*)alloc((size_t)N * 4);
    float*        pbuf     = (float*)alloc((size_t)N * 4);
    float*        qbuf     = (float*)alloc((size_t)N * 4);
    int*          bump     = (int*)alloc(64);
    int*          btail    = (int*)alloc((size_t)NBUCK * 4);

    // Output layout: new_x[N*128] | cluster[N] | is_rep[N] | new_row[E] | new_col[E] | edge_valid[E] | edge_weight[E]
    float* out       = (float*)d_out;
    float* o_newx    = out;
    float* o_cluster = out + (size_t)N * IN_CH;
    float* o_isrep   = o_cluster + N;
    float* o_nrow    = o_isrep + N;
    float* o_ncol    = o_nrow + E;
    float* o_valid   = o_ncol + E;
    float* o_w       = o_valid + E;

    const int T = 256;
    const int TS = 512;
    hipLaunchKernelGGL(proj_kernel, dim3((N * 64 + T - 1) / T), dim3(T), 0, stream,
                       x, w_src, w_dst, pbuf, qbuf,
                       wsuit, cluster, partner, s_rep, bump, btail, N);
    hipLaunchKernelGGL(score_kernel, dim3((E + TS - 1) / TS), dim3(TS), 0, stream,
                       row, col, pbuf, qbuf, bptr, score, rc,
                       btail, bucket, bcap, E);
    hipLaunchKernelGGL(slot_kernel, dim3(NBUCK), dim3(512), 0, stream,
                       bucket, btail, bcap, score, node_max, denom, bump, seg, N);
    hipLaunchKernelGGL(norm_key_kernel, dim3((E + T - 1) / T), dim3(T), 0, stream,
                       row, score, node_max, denom, norm, keyn, E);
    const int bpx = 40;                     // blocks per XCD slot
    hipLaunchKernelGGL(csr_scatter_kernel, dim3(8 * bpx), dim3(T), 0, stream,
                       bucket, btail, bcap, keyn, rc, seg, adj, bpx);
    hipLaunchKernelGGL(suitor_kernel, dim3((N * 32 + T - 1) / T), dim3(T), 0, stream,
                       seg, adj, rc, wsuit, N);
    hipLaunchKernelGGL(extract_kernel, dim3((N + T - 1) / T), dim3(T), 0, stream,
                       rc, norm, wsuit, cluster, partner, s_rep, N);
    const int NB1 = (N * 32 + T - 1) / T;
    const int NB2 = (E + T - 1) / T;
    hipLaunchKernelGGL(out_kernel, dim3(NB1 + NB2), dim3(T), 0, stream,
                       x, cluster, partner, s_rep, row, col, ew,
                       o_newx, o_cluster, o_isrep, o_nrow, o_ncol, o_valid, o_w, N, E, NB1);
    (void)ws_size; (void)out_size; (void)n_in_args;
}